// Round 8
// baseline (329.258 us; speedup 1.0000x reference)
//
#include <hip/hip_runtime.h>
#include <hip/hip_bf16.h>

#define EMB   1024
#define HEADS 16
#define HDIM  64
#define BB    4
#define SS    2048
#define MROWS (BB*SS)   // 8192

typedef __bf16 bf16_t;
typedef __bf16 bf16x4_t __attribute__((ext_vector_type(4)));
typedef __bf16 bf16x8   __attribute__((ext_vector_type(8)));
typedef float  f32x4    __attribute__((ext_vector_type(4)));

// async global->LDS, 16B/lane; LDS base wave-uniform, HW adds lane*16
__device__ __forceinline__ void glds16(const void* g, void* l) {
  __builtin_amdgcn_global_load_lds(
      (const __attribute__((address_space(1))) void*)g,
      (__attribute__((address_space(3))) void*)l, 16, 0, 0);
}

// ---------------------------------------------------------------------------
// Multi-tensor fp32->bf16 cast. z < nact: 8M-elem activations (4096 blocks);
// z >= nact: 1M-elem weights (first 512 blocks active).
// ---------------------------------------------------------------------------
__launch_bounds__(256)
__global__ void cast_multi(const float* s0, const float* s1, const float* s2,
                           const float* s3, const float* s4, const float* s5,
                           const float* s6,
                           bf16_t* d0, bf16_t* d1, bf16_t* d2, bf16_t* d3,
                           bf16_t* d4, bf16_t* d5, bf16_t* d6, int nact) {
  const int z = blockIdx.z;
  if (z >= nact && blockIdx.x >= 512) return;
  const float* ss[7] = {s0, s1, s2, s3, s4, s5, s6};
  bf16_t*      dd[7] = {d0, d1, d2, d3, d4, d5, d6};
  const float* s = ss[z];
  bf16_t*      d = dd[z];
  const int i = (blockIdx.x*256 + threadIdx.x) * 8;
  const f32x4 a = *(const f32x4*)&s[i];
  const f32x4 b = *(const f32x4*)&s[i+4];
  bf16x8 r;
  r[0]=(bf16_t)a[0]; r[1]=(bf16_t)a[1]; r[2]=(bf16_t)a[2]; r[3]=(bf16_t)a[3];
  r[4]=(bf16_t)b[0]; r[5]=(bf16_t)b[1]; r[6]=(bf16_t)b[2]; r[7]=(bf16_t)b[3];
  *(bf16x8*)&d[i] = r;
}

__launch_bounds__(256)
__global__ void cast_f32_bf16(const float* __restrict__ src, bf16_t* __restrict__ dst) {
  const int i = (blockIdx.x*256 + threadIdx.x) * 8;
  const f32x4 a = *(const f32x4*)&src[i];
  const f32x4 b = *(const f32x4*)&src[i+4];
  bf16x8 r;
  r[0]=(bf16_t)a[0]; r[1]=(bf16_t)a[1]; r[2]=(bf16_t)a[2]; r[3]=(bf16_t)a[3];
  r[4]=(bf16_t)b[0]; r[5]=(bf16_t)b[1]; r[6]=(bf16_t)b[2]; r[7]=(bf16_t)b[3];
  *(bf16x8*)&dst[i] = r;
}

// ---------------------------------------------------------------------------
// Shared GEMM core, BK=64: acc[4][4] += A_tile @ W_tile^T over K=EMB.
// 128x128 tile, 16 K-iters, 32 MFMA between barriers (half the barrier count
// of BK=32).  Each 128x64 tile is stored as two 32-wide subtiles so the
// m97-verified 64B-row-stride ds_read_b128 pattern is kept.  LDS 32KB.
// ---------------------------------------------------------------------------
__device__ __forceinline__ void gemm_core(const bf16_t* __restrict__ A,
                                          const bf16_t* __restrict__ W,
                                          bf16_t* As, bf16_t* Bs,
                                          f32x4 acc[4][4],
                                          int bm0, int bn0,
                                          int wave, int lane) {
  const int quad = lane >> 4, l16 = lane & 15;
  const int wm = wave >> 1, wn = wave & 1;
  for (int k0 = 0; k0 < EMB; k0 += 64) {
#pragma unroll
    for (int ks = 0; ks < 2; ++ks)
#pragma unroll
      for (int c = 0; c < 2; ++c) {
        const int j   = wave*2 + c;          // 16-row group 0..7
        const int row = j*16 + (lane >> 2);
        const int col = ks*32 + (lane & 3)*8;
        glds16(A + (size_t)(bm0 + row)*EMB + k0 + col, &As[ks*4096 + j*512]);
        glds16(W + (size_t)(bn0 + row)*EMB + k0 + col, &Bs[ks*4096 + j*512]);
      }
    __syncthreads();

#pragma unroll
    for (int ks = 0; ks < 2; ++ks) {
      bf16x8 a[4], b[4];
#pragma unroll
      for (int t = 0; t < 4; ++t) {
        a[t] = *(const bf16x8*)&As[ks*4096 + (wm*64 + t*16 + l16)*32 + quad*8];
        b[t] = *(const bf16x8*)&Bs[ks*4096 + (wn*64 + t*16 + l16)*32 + quad*8];
      }
#pragma unroll
      for (int mt = 0; mt < 4; ++mt)
#pragma unroll
        for (int nt = 0; nt < 4; ++nt)
          acc[mt][nt] = __builtin_amdgcn_mfma_f32_16x16x32_bf16(a[mt], b[nt], acc[mt][nt], 0, 0, 0);
    }
    __syncthreads();
  }
}

// ---------------------------------------------------------------------------
// Fused projection GEMM with XCD-aware swizzle (each (z,bm) A-panel owned by
// one XCD; W(z) hot in that XCD's L2).  z (+zbase): 0=Q (sscale), 1=K, 2=V
// (packed-V^T epilogue in the attention B-operand chunk order).
// ---------------------------------------------------------------------------
__launch_bounds__(256)
__global__ void gemm_qkv(const bf16_t* A0, const bf16_t* A1, const bf16_t* A2,
                         const bf16_t* W0, const bf16_t* W1, const bf16_t* W2,
                         bf16_t* C0, bf16_t* C1, bf16_t* C2,
                         float sscale, int zbase) {
  __shared__ __align__(16) bf16_t As[128*64];
  __shared__ __align__(16) bf16_t Bs[128*64];
  const int tid  = threadIdx.x;
  const int wave = tid >> 6, lane = tid & 63;
  const int quad = lane >> 4, l16 = lane & 15;
  const int wm = wave >> 1, wn = wave & 1;

  // XCD swizzle: fid -> (z, bm, bn)
  const int fid = blockIdx.x + 8*(blockIdx.y + 64*blockIdx.z);
  const int xcd = fid & 7, s = fid >> 3;
  const int bn0 = (s & 7) * 128;
  const int p   = xcd + 8*(s >> 3);            // (z,bm) pair, unique per XCD
  const int z   = (p >> 6) + zbase;
  const int bm0 = (p & 63) * 128;

  const bf16_t* A = (z == 0) ? A0 : (z == 1) ? A1 : A2;
  const bf16_t* W = (z == 0) ? W0 : (z == 1) ? W1 : W2;
  bf16_t*       C = (z == 0) ? C0 : (z == 1) ? C1 : C2;
  const float oscale = (z == 0) ? sscale : 1.0f;

  f32x4 acc[4][4] = {};
  gemm_core(A, W, As, Bs, acc, bm0, bn0, wave, lane);

  if (z == 2) {
    // packed-V^T epilogue: acc[mt][nt][r] = V[s=bm0+wm*64+mt*16+quad*4+r][d]
    const int bb = bm0 >> 11;                    // batch (2048 rows each)
    const int T  = ((bm0 & 2047) >> 6) + wm;     // 64-key tile within batch
    const int h  = (bn0 >> 6) + wn;              // head (64 cols each)
    bf16_t* base = C + ((size_t)(bb*HEADS + h)*32 + T)*4096;
#pragma unroll
    for (int ks = 0; ks < 2; ++ks)
#pragma unroll
      for (int nt = 0; nt < 4; ++nt) {
        bf16x8 v;
#pragma unroll
        for (int r = 0; r < 4; ++r) {
          v[r]     = (bf16_t)acc[2*ks][nt][r];
          v[4 + r] = (bf16_t)acc[2*ks + 1][nt][r];
        }
        *(bf16x8*)&base[((nt*2 + ks)*64 + quad*16 + l16)*8] = v;
      }
  } else {
    // row-major epilogue: C/D layout col=l16, row=quad*4+reg
#pragma unroll
    for (int mt = 0; mt < 4; ++mt) {
      const int row = bm0 + wm*64 + mt*16 + quad*4;
#pragma unroll
      for (int nt = 0; nt < 4; ++nt) {
        const int col = bn0 + wn*64 + nt*16 + l16;
#pragma unroll
        for (int r = 0; r < 4; ++r)
          C[(size_t)(row + r)*EMB + col] = (bf16_t)(acc[mt][nt][r] * oscale);
      }
    }
  }
}

// output GEMM: fp32 C, row-major, XCD swizzle (8 bm-panels per XCD, W hot)
__launch_bounds__(256)
__global__ void gemm_out(const bf16_t* __restrict__ A, const bf16_t* __restrict__ W,
                         float* __restrict__ C) {
  __shared__ __align__(16) bf16_t As[128*64];
  __shared__ __align__(16) bf16_t Bs[128*64];
  const int tid  = threadIdx.x;
  const int wave = tid >> 6, lane = tid & 63;
  const int quad = lane >> 4, l16 = lane & 15;
  const int wm = wave >> 1, wn = wave & 1;

  const int fid = blockIdx.x + 8*blockIdx.y;
  const int xcd = fid & 7, s = fid >> 3;
  const int bn0 = (s & 7) * 128;
  const int bm0 = (xcd*8 + (s >> 3)) * 128;

  f32x4 acc[4][4] = {};
  gemm_core(A, W, As, Bs, acc, bm0, bn0, wave, lane);

#pragma unroll
  for (int mt = 0; mt < 4; ++mt) {
    const int row = bm0 + wm*64 + mt*16 + quad*4;
#pragma unroll
    for (int nt = 0; nt < 4; ++nt) {
      const int col = bn0 + wn*64 + nt*16 + l16;
#pragma unroll
      for (int r = 0; r < 4; ++r)
        C[(size_t)(row + r)*EMB + col] = acc[mt][nt][r];
    }
  }
}

// ---------------------------------------------------------------------------
// Flash attention, Q-tile 128 (4 waves x 32 rows), K-tile 64, DOUBLE-BUFFERED
// staging: loop shape = { barrier; stage(next buf); compute(cur) } so the
// vmcnt(0) drain at each barrier waits on loads issued one full compute phase
// earlier.  One barrier per tile.  S^T = MFMA(A=K, B=Q) gives the P^T
// B-operand layout directly; packed V^T (from the V-GEMM epilogue) is the
// A-operand of O^T = V^T P^T with zero data movement.  No-max softmax (scale
// folded into Q projection), raw v_exp_f32, deferred l-reduction.
// XCD swizzle: all 16 q-blocks of one (b,h) on one XCD (K/V L2-resident).
// Qp and Cx alias (disjoint per-block slices, read-before-write).
// ---------------------------------------------------------------------------
__launch_bounds__(256)
__global__ void attn(const bf16_t* Qp, const bf16_t* __restrict__ Kp,
                     const bf16_t* __restrict__ Vt, bf16_t* Cx) {
  __shared__ __align__(16) bf16_t Ks[2][4096];  // dbuf [d-half][key][32] 16KB
  __shared__ __align__(16) bf16_t Vs[2][4096];  // dbuf packed V^T chunks 16KB

  const int tid  = threadIdx.x;
  const int wave = tid >> 6, lane = tid & 63;
  const int quad = lane >> 4, l16 = lane & 15;

  // XCD swizzle: fid -> (b, h, q-block); gridDim = (16, 16, 4)
  const int fid  = blockIdx.x + 16*(blockIdx.y + 16*blockIdx.z);
  const int xcd  = fid & 7, s = fid >> 3;
  const int q0   = (s & 15) * 128;
  const int pair = xcd*8 + (s >> 4);    // 0..63, unique per XCD
  const int h    = pair & 15;
  const int b    = pair >> 4;

  // Q fragments (B-operand of S^T): lane l16 = qrow, k = d = quad*8+j (+32ks)
  bf16x8 qf[2][2];
#pragma unroll
  for (int mb = 0; mb < 2; ++mb) {
    const size_t qr = (size_t)(b*SS + q0 + wave*32 + mb*16 + l16)*EMB + h*HDIM;
#pragma unroll
    for (int ks = 0; ks < 2; ++ks)
      qf[mb][ks] = *(const bf16x8*)&Qp[qr + ks*32 + quad*8];
  }

  const bf16_t* Kb = Kp + (size_t)b*SS*EMB + h*HDIM;
  const bf16_t* Vb = Vt + ((size_t)(b*HEADS + h)*32)*4096;

  f32x4 o[2][4] = {};          // O^T: lane l16 = qrow, row = d = quad*4+r
  float lsum[2] = {0.f, 0.f};

  // stage K (row-major halves) + packed V^T (identity copy): 4 glds16/wave
  auto stage = [&](int buf, int t0) {
#pragma unroll
    for (int c = 0; c < 2; ++c) {
      const int i   = wave + c*4;
      const int r   = (i & 3)*16 + (lane >> 2);
      const int col = (lane & 3)*8;
      glds16(Kb + (size_t)(t0 + r)*EMB + c*32 + col, &Ks[buf][i*512]);
      glds16(Vb + (size_t)(t0 >> 6)*4096 + i*512 + lane*8, &Vs[buf][i*512]);
    }
  };

  auto compute = [&](int buf) {
    const bf16_t* Kss = Ks[buf];
    const bf16_t* Vss = Vs[buf];
    // S^T = K Q^T : A = K-frag (lane l16 = key), B = Q-frag  (16 MFMA)
    f32x4 st[2][4] = {};
#pragma unroll
    for (int cb = 0; cb < 4; ++cb) {
      const bf16x8 kf0 = *(const bf16x8*)&Kss[(cb*16 + l16)*32 + quad*8];
      const bf16x8 kf1 = *(const bf16x8*)&Kss[2048 + (cb*16 + l16)*32 + quad*8];
#pragma unroll
      for (int mb = 0; mb < 2; ++mb) {
        st[mb][cb] = __builtin_amdgcn_mfma_f32_16x16x32_bf16(kf0, qf[mb][0], st[mb][cb], 0, 0, 0);
        st[mb][cb] = __builtin_amdgcn_mfma_f32_16x16x32_bf16(kf1, qf[mb][1], st[mb][cb], 0, 0, 0);
      }
    }
    // softmax (no-max): p = exp2(s); pack P^T B-fragments directly from regs
    bf16x8 pb[2][2];
#pragma unroll
    for (int mb = 0; mb < 2; ++mb) {
      float ls = 0.f;
#pragma unroll
      for (int kb = 0; kb < 4; ++kb)
#pragma unroll
        for (int r = 0; r < 4; ++r) {
          const float p = __builtin_amdgcn_exp2f(st[mb][kb][r]);
          st[mb][kb][r] = p;
          ls += p;
        }
      lsum[mb] += ls;
#pragma unroll
      for (int ks = 0; ks < 2; ++ks)
#pragma unroll
        for (int r = 0; r < 4; ++r) {
          pb[mb][ks][r]     = (bf16_t)st[mb][2*ks][r];
          pb[mb][ks][4 + r] = (bf16_t)st[mb][2*ks + 1][r];
        }
    }
    // O^T += V^T P^T : A = packed V^T chunk, B = pb  (16 MFMA)
#pragma unroll
    for (int ks = 0; ks < 2; ++ks)
#pragma unroll
      for (int dt = 0; dt < 4; ++dt) {
        const bf16x8 vf = *(const bf16x8*)&Vss[((dt*2 + ks)*64 + quad*16 + l16)*8];
#pragma unroll
        for (int mb = 0; mb < 2; ++mb)
          o[mb][dt] = __builtin_amdgcn_mfma_f32_16x16x32_bf16(vf, pb[mb][ks], o[mb][dt], 0, 0, 0);
      }
  };

  stage(0, 0);
  for (int t = 0; t < SS/64; t += 2) {
    __syncthreads();                     // drains stage(t) (issued 1 phase ago)
    if (t + 1 < SS/64) stage(1, (t+1)*64);
    compute(0);
    __syncthreads();                     // drains stage(t+1)
    if (t + 2 < SS/64) stage(0, (t+2)*64);
    compute(1);
  }

  // l-reduce across quads (lanes sharing l16) + write O^T as [row][h*64+d]
#pragma unroll
  for (int mb = 0; mb < 2; ++mb) {
    float l = lsum[mb];
    l += __shfl_xor(l, 16, 64);
    l += __shfl_xor(l, 32, 64);
    const float inv = 1.0f / l;
    const size_t row = (size_t)(b*SS + q0 + wave*32 + mb*16 + l16)*EMB + h*HDIM;
#pragma unroll
    for (int dt = 0; dt < 4; ++dt) {
      bf16x4_t v;
#pragma unroll
      for (int r = 0; r < 4; ++r) v[r] = (bf16_t)(o[mb][dt][r] * inv);
      *(bf16x4_t*)&Cx[row + dt*16 + quad*4] = v;
    }
  }
}

// ---------------------------------------------------------------------------
extern "C" void kernel_launch(void* const* d_in, const int* in_sizes, int n_in,
                              void* d_out, int out_size, void* d_ws, size_t ws_size,
                              hipStream_t stream) {
  (void)in_sizes; (void)n_in; (void)out_size;
  const float* query = (const float*)d_in[0];
  const float* key   = (const float*)d_in[1];
  const float* value = (const float*)d_in[2];
  const float* WqF   = (const float*)d_in[3];
  const float* WkF   = (const float*)d_in[4];
  const float* WvF   = (const float*)d_in[5];
  const float* WoF   = (const float*)d_in[6];

  const size_t AN = (size_t)MROWS*EMB;   // 8M elems
  const size_t WN = (size_t)EMB*EMB;     // 1M elems
  float* out = (float*)d_out;
  bf16_t* S5 = (bf16_t*)d_out;           // d_out first 16MB as bf16 scratch
  bf16_t* S6 = S5 + AN;                  // d_out second 16MB

  const float sscale = 0.125f * 1.44269504f;  // 1/sqrt(64)*log2(e) into Q

  const dim3 gqkv(EMB/128, MROWS/128, 3);
  const dim3 gqk (EMB/128, MROWS/128, 2);
  const dim3 gv  (EMB/128, MROWS/128, 1);
  const dim3 gg  (EMB/128, MROWS/128);
  const dim3 gattn(SS/128, HEADS, BB);

  if (ws_size >= (size_t)(4*AN + 4*WN) * sizeof(bf16_t)) {
    // ---- full-fusion path (ws >= 72MB): qb|kb|vb|S2|W in ws -------------
    bf16_t* qb  = (bf16_t*)d_ws;
    bf16_t* kb  = qb + AN;
    bf16_t* vb  = kb + AN;
    bf16_t* S2  = vb + AN;
    bf16_t* Wqb = S2 + AN;
    bf16_t* Wkb = Wqb + WN;
    bf16_t* Wvb = Wkb + WN;
    bf16_t* Wob = Wvb + WN;

    cast_multi<<<dim3(AN/2048, 1, 7), 256, 0, stream>>>(
        query, key, value, WqF, WkF, WvF, WoF,
        qb, kb, vb, Wqb, Wkb, Wvb, Wob, 3);
    gemm_qkv<<<gqkv, 256, 0, stream>>>(qb, kb, vb, Wqb, Wkb, Wvb,
                                       S2, S6, S5, sscale, 0);
    attn<<<gattn, 256, 0, stream>>>(S2, S6, S5, S2);
    gemm_out<<<gg, 256, 0, stream>>>(S2, Wob, out);
  } else {
    // ---- fallback path (ws >= 40MB proven): S1|S2|W in ws ---------------
    bf16_t* S1  = (bf16_t*)d_ws;
    bf16_t* S2  = S1 + AN;
    bf16_t* Wqb = S2 + AN;
    bf16_t* Wkb = Wqb + WN;
    bf16_t* Wvb = Wkb + WN;
    bf16_t* Wob = Wvb + WN;

    // z0: query->S1 (ws), z1: key->S5 (d_out), z2..5: weights
    cast_multi<<<dim3(AN/2048, 1, 6), 256, 0, stream>>>(
        query, key, WqF, WkF, WvF, WoF, WoF,
        S1, S5, Wqb, Wkb, Wvb, Wob, Wob, 2);
    gemm_qkv<<<gqk, 256, 0, stream>>>(S1, S5, S1, Wqb, Wkb, Wvb,
                                      S2, S6, S5, sscale, 0);   // Qp=S2, Kp=S6
    cast_f32_bf16<<<dim3(AN/2048), 256, 0, stream>>>(value, S1); // vb=S1 (qb dead)
    gemm_qkv<<<gv, 256, 0, stream>>>(S1, S1, S1, Wvb, Wvb, Wvb,
                                     S5, S5, S5, 1.0f, 2);      // Vt=S5 (kb dead)
    attn<<<gattn, 256, 0, stream>>>(S2, S6, S5, S2);            // Cx=S2
    gemm_out<<<gg, 256, 0, stream>>>(S2, Wob, out);
  }
}